// Round 15
// baseline (445.767 us; speedup 1.0000x reference)
//
#include <hip/hip_runtime.h>
#include <hip/hip_bf16.h>

#define NN 16384     // nodes
#define FD 512       // feature dim
#define EMB 128      // embed_dim (dense1)
#define OD 64        // out_dim
#define NE 524288    // edges (self-loops handled analytically)
#define NCHK 128     // xtw n-chunks (128 rows each)

typedef __bf16 bf16x8 __attribute__((ext_vector_type(8)));
typedef float f32x4 __attribute__((ext_vector_type(4)));
typedef unsigned short u16;

__device__ inline float bfu2f(u16 u) {
    unsigned int x = (unsigned int)u << 16;
    float f;
    __builtin_memcpy(&f, &x, 4);
    return f;
}

// ===== prep: xtw partials (1024 blocks, 4/CU) | dst hist | x->bf16 | WgT ===
__global__ __launch_bounds__(256) void k_prep(
    const float* __restrict__ x, __hip_bfloat16* __restrict__ xbf,
    const float* __restrict__ Wg, __hip_bfloat16* __restrict__ WgT,
    const int* __restrict__ ei, int* __restrict__ deg,
    const float* __restrict__ W1, float* __restrict__ part) {
    __shared__ float xs[4][64];
    __shared__ float wsh[4][EMB];
    int b = blockIdx.x;
    int t = threadIdx.x;
    if (b < NCHK * 8) {                              // xtw partial tile
        int fb = b & 7, nc = b >> 3;                 // 8 f-tiles x 128 n-chunks
        int f0 = fb * 64, nb = nc * 128;             // 128 rows per chunk
        int eb = (t & 15) * 8;                       // 8 e per thread
        int fbase = (t >> 4) * 4;                    // 4 f per thread
        float acc[4][8] = {};
        for (int n4 = 0; n4 < 128; n4 += 4) {        // 32 iterations
            { int nn = t >> 6, ff = t & 63;
              xs[nn][ff] = x[(size_t)(nb + n4 + nn) * FD + f0 + ff]; }
#pragma unroll
            for (int j = 0; j < 2; ++j) {
                int idx = t + j * 256;
                wsh[idx >> 7][idx & 127] = W1[(size_t)(nb + n4 + (idx >> 7)) * EMB + (idx & 127)];
            }
            __syncthreads();
#pragma unroll
            for (int nn = 0; nn < 4; ++nn) {
                float xv[4], wv[8];
#pragma unroll
                for (int i = 0; i < 4; ++i) xv[i] = xs[nn][fbase + i];
#pragma unroll
                for (int j = 0; j < 8; ++j) wv[j] = wsh[nn][eb + j];
#pragma unroll
                for (int i = 0; i < 4; ++i)
#pragma unroll
                    for (int j = 0; j < 8; ++j) acc[i][j] += xv[i] * wv[j];
            }
            __syncthreads();
        }
#pragma unroll
        for (int i = 0; i < 4; ++i) {
            float* dst = &part[((size_t)nc * FD + f0 + fbase + i) * EMB + eb];
            *reinterpret_cast<f32x4*>(dst) = *reinterpret_cast<f32x4*>(&acc[i][0]);
            *reinterpret_cast<f32x4*>(dst + 4) = *reinterpret_cast<f32x4*>(&acc[i][4]);
        }
        return;
    }
    b -= NCHK * 8;
    if (b < NE / 256) {                              // histogram of dst
        int i = b * 256 + t;
        atomicAdd(deg + ei[NE + i], 1);
        return;
    }
    b -= NE / 256;
    if (b < NN * FD / 2048) {                        // x -> bf16
        size_t i = ((size_t)b * 256 + t) * 8;
        float4 v0 = *reinterpret_cast<const float4*>(x + i);
        float4 v1 = *reinterpret_cast<const float4*>(x + i + 4);
        __hip_bfloat16 o[8];
        o[0] = __float2bfloat16(v0.x); o[1] = __float2bfloat16(v0.y);
        o[2] = __float2bfloat16(v0.z); o[3] = __float2bfloat16(v0.w);
        o[4] = __float2bfloat16(v1.x); o[5] = __float2bfloat16(v1.y);
        o[6] = __float2bfloat16(v1.z); o[7] = __float2bfloat16(v1.w);
        *reinterpret_cast<uint4*>(xbf + i) = *reinterpret_cast<const uint4*>(o);
        return;
    }
    b -= NN * FD / 2048;
    {                                                // WgT[c][k] = Wg[k][c]
        int c = t >> 2;
        int k0 = (t & 3) * 128;
        for (int j = 0; j < 128; ++j)
            WgT[c * 512 + k0 + j] = __float2bfloat16(Wg[(size_t)(k0 + j) * OD + c]);
    }
}

// ---------------- exclusive scan deg[NN] -> row_start (parallel) -----------
__global__ __launch_bounds__(256) void k_scan(const int* __restrict__ deg,
                                              int* __restrict__ row_start) {
    __shared__ int part[256];
    int t = threadIdx.x;
    int base = t * 64;                                   // NN/256 = 64
    int s = 0;
    for (int j = 0; j < 64; ++j) s += deg[base + j];
    part[t] = s;
    __syncthreads();
    for (int off = 1; off < 256; off <<= 1) {
        int v = (t >= off) ? part[t - off] : 0;
        __syncthreads();
        part[t] += v;
        __syncthreads();
    }
    int run = part[t] - s;                               // exclusive
    if (t == 255) row_start[NN] = part[255];
    for (int j = 0; j < 64; ++j) { row_start[base + j] = run; run += deg[base + j]; }
}

// ===== mid: CSR scatter | h = xbf@Wg MFMA + a_src/a_dst | h2 reduce ========
__global__ __launch_bounds__(256) void k_mid(
    const int* __restrict__ ei, const int* __restrict__ row_start,
    int* __restrict__ cursor, int* __restrict__ ssrc,
    const __hip_bfloat16* __restrict__ xbf, const __hip_bfloat16* __restrict__ WgT,
    const float* __restrict__ att_s, const float* __restrict__ att_d,
    __hip_bfloat16* __restrict__ hbf, float* __restrict__ a_src, float* __restrict__ a_dst,
    const float* __restrict__ part, const float* __restrict__ b1,
    const float* __restrict__ W2, const float* __restrict__ b2,
    __hip_bfloat16* __restrict__ h2bf) {
    __shared__ float hv[4][EMB];
    int b = blockIdx.x;
    int t = threadIdx.x;
    if (b < NE / 256) {                              // scatter
        int i = b * 256 + t;
        int d = ei[NE + i];
        int pos = atomicAdd(cursor + d, 1);
        ssrc[row_start[d] + pos] = ei[i];
        return;
    }
    b -= NE / 256;
    int w = t >> 6, l = t & 63;
    if (b < NN / 64) {                               // hmm MFMA, 64 rows/block
        int lg = l >> 4, lm = l & 15;
        int r0 = b * 64 + w * 16;
        const bf16x8* Xp = reinterpret_cast<const bf16x8*>(xbf);
        const bf16x8* Wp = reinterpret_cast<const bf16x8*>(WgT);
        bf16x8 a[16];
        size_t abase = (size_t)(r0 + lm) * 64 + lg;
#pragma unroll
        for (int kc = 0; kc < 16; ++kc) a[kc] = Xp[abase + kc * 4];
        f32x4 acc[4];
#pragma unroll
        for (int j = 0; j < 4; ++j) {
            f32x4 c = {0.f, 0.f, 0.f, 0.f};
            size_t bbase = (size_t)(j * 16 + lm) * 64 + lg;
#pragma unroll
            for (int kc = 0; kc < 16; ++kc)
                c = __builtin_amdgcn_mfma_f32_16x16x32_bf16(a[kc], Wp[bbase + kc * 4], c, 0, 0, 0);
            acc[j] = c;
        }
#pragma unroll
        for (int j = 0; j < 4; ++j)
#pragma unroll
            for (int reg = 0; reg < 4; ++reg)
                hbf[(size_t)(r0 + lg * 4 + reg) * OD + j * 16 + lm] = __float2bfloat16(acc[j][reg]);
        float ats0 = att_s[lm], ats1 = att_s[16 + lm], ats2 = att_s[32 + lm], ats3 = att_s[48 + lm];
        float atd0 = att_d[lm], atd1 = att_d[16 + lm], atd2 = att_d[32 + lm], atd3 = att_d[48 + lm];
#pragma unroll
        for (int reg = 0; reg < 4; ++reg) {
            float ps = acc[0][reg] * ats0 + acc[1][reg] * ats1 + acc[2][reg] * ats2 + acc[3][reg] * ats3;
            float pd = acc[0][reg] * atd0 + acc[1][reg] * atd1 + acc[2][reg] * atd2 + acc[3][reg] * atd3;
#pragma unroll
            for (int off = 1; off < 16; off <<= 1) {
                ps += __shfl_xor(ps, off, 64);
                pd += __shfl_xor(pd, off, 64);
            }
            if (lm == 0) {
                int r = r0 + lg * 4 + reg;
                a_src[r] = ps;
                a_dst[r] = pd;
            }
        }
        return;
    }
    b -= NN / 64;
    {                                                // h2: reduce 128 partials
        int f = b * 4 + w;
        float s0 = 0.f, s1 = 0.f;
        for (int nc = 0; nc < NCHK; ++nc) {
            const float* p = part + ((size_t)nc * FD + f) * EMB;
            s0 += p[l];
            s1 += p[l + 64];
        }
        s0 += b1[l]; s1 += b1[l + 64];
        hv[w][l] = s0 > 0.f ? s0 : 0.f;
        hv[w][l + 64] = s1 > 0.f ? s1 : 0.f;
        __syncthreads();
        float acc = b2[l];
        const float* myhv = hv[w];
        for (int e = 0; e < EMB; ++e)
            acc += myhv[e] * W2[e * OD + l];
        h2bf[(size_t)f * OD + l] = __float2bfloat16(acc);
    }
}

// ------- fused softmax+aggregate+bias+leaky+bf16: one wave per dst node ----
__global__ __launch_bounds__(256) void k_aggcsr(
    const int* __restrict__ row_start, const int* __restrict__ ssrc,
    const float* __restrict__ a_src, const float* __restrict__ a_dst,
    const u16* __restrict__ hb, const float* __restrict__ bg,
    __hip_bfloat16* __restrict__ ebf) {
    int node = blockIdx.x * 4 + (threadIdx.x >> 6);
    int lane = threadIdx.x & 63;
    float ad = a_dst[node];
    float e0 = a_src[node] + ad;                 // self loop
    e0 = e0 > 0.f ? e0 : 0.5f * e0;
    float p0 = __expf(e0);
    float denom = p0;
    float acc = p0 * bfu2f(hb[(size_t)node * OD + lane]);
    int j0 = row_start[node], j1 = row_start[node + 1];
    int j = j0;
    for (; j + 2 <= j1; j += 2) {
        int sA = ssrc[j], sB = ssrc[j + 1];
        float hA = bfu2f(hb[(size_t)sA * OD + lane]);
        float hB = bfu2f(hb[(size_t)sB * OD + lane]);
        float eA = a_src[sA] + ad, eB = a_src[sB] + ad;
        eA = eA > 0.f ? eA : 0.5f * eA;
        eB = eB > 0.f ? eB : 0.5f * eB;
        float pA = __expf(eA), pB = __expf(eB);
        denom += pA + pB;
        acc += pA * hA + pB * hB;
    }
    if (j < j1) {
        int s = ssrc[j];
        float e = a_src[s] + ad;
        e = e > 0.f ? e : 0.5f * e;
        float pv = __expf(e);
        denom += pv;
        acc += pv * bfu2f(hb[(size_t)s * OD + lane]);
    }
    float v = acc * __builtin_amdgcn_rcpf(denom) + bg[lane];
    v = v > 0.f ? v : 0.01f * v;                 // embed leaky_relu 0.01
    ebf[(size_t)node * OD + lane] = __float2bfloat16(v);
}

// ===== merged output GEMMs: X_hat tiles (512 blocks) then A_hat (16384) ====
// A_hat tile = 64 rows x 256 cols (4 waves x 16 rows). Epilogue: 2 phases of
// 8 rows x 256 cols staged in per-wave LDS (8.3KB/wave -> 4 blocks/CU);
// drain instr = 1 row-segment of 1KB FULLY contiguous (64 lanes x 16B).
// Col-fast grid: adjacent blocks write adjacent 1KB chunks of a 64-row band.
__global__ __launch_bounds__(256) void k_mmAX(const __hip_bfloat16* __restrict__ ebf,
                                              const __hip_bfloat16* __restrict__ h2bf,
                                              float* __restrict__ outA,
                                              float* __restrict__ outX) {
    __shared__ float ls[4][2176];                    // max(32*68, 8*260) floats
    int w = threadIdx.x >> 6, l = threadIdx.x & 63;
    int lg = l >> 4, lm = l & 15;
    float* myl = ls[w];
    const bf16x8* Ap = reinterpret_cast<const bf16x8*>(ebf);
    if (blockIdx.x < 512) {                          // ---- X_hat tile ----
        int bid = blockIdx.x;
        int i0 = (bid >> 2) * 128 + w * 32;
        int j0 = (bid & 3) * 128;
        const bf16x8* Bp = reinterpret_cast<const bf16x8*>(h2bf);
        size_t arow = (size_t)(i0 + lm) * 8;
        bf16x8 a0 = Ap[arow + lg];
        bf16x8 a1 = Ap[arow + 4 + lg];
        bf16x8 a2 = Ap[arow + 128 + lg];
        bf16x8 a3 = Ap[arow + 128 + 4 + lg];
        f32x4 accL[8], accH[8];
#pragma unroll
        for (int ct = 0; ct < 8; ++ct) {
            size_t brow = (size_t)(j0 + ct * 16 + lm) * 8;
            bf16x8 b0 = Bp[brow + lg];
            bf16x8 b1 = Bp[brow + 4 + lg];
            f32x4 cL = {0.f, 0.f, 0.f, 0.f};
            f32x4 cH = {0.f, 0.f, 0.f, 0.f};
            cL = __builtin_amdgcn_mfma_f32_16x16x32_bf16(a0, b0, cL, 0, 0, 0);
            cL = __builtin_amdgcn_mfma_f32_16x16x32_bf16(a1, b1, cL, 0, 0, 0);
            cH = __builtin_amdgcn_mfma_f32_16x16x32_bf16(a2, b0, cH, 0, 0, 0);
            cH = __builtin_amdgcn_mfma_f32_16x16x32_bf16(a3, b1, cH, 0, 0, 0);
            accL[ct] = cL;
            accH[ct] = cH;
        }
#pragma unroll
        for (int ph = 0; ph < 2; ++ph) {
            if (ph == 1) {
                asm volatile("s_waitcnt lgkmcnt(0)" ::: "memory");
                __builtin_amdgcn_sched_barrier(0);
            }
#pragma unroll
            for (int c4 = 0; c4 < 4; ++c4) {
                int ct = ph * 4 + c4;
                int col = c4 * 16 + lm;
#pragma unroll
                for (int reg = 0; reg < 4; ++reg) {
                    int row = lg * 4 + reg;
                    myl[row * 68 + col] = accL[ct][reg];
                    myl[(row + 16) * 68 + col] = accH[ct][reg];
                }
            }
            asm volatile("s_waitcnt lgkmcnt(0)" ::: "memory");
            __builtin_amdgcn_sched_barrier(0);
#pragma unroll
            for (int i = 0; i < 8; ++i) {
                int row = i * 4 + lg;
                f32x4 v = *reinterpret_cast<const f32x4*>(&myl[row * 68 + lm * 4]);
                float* dst = &outX[(size_t)(i0 + row) * FD + j0 + ph * 64 + lm * 4];
                __builtin_nontemporal_store(v, reinterpret_cast<f32x4*>(dst));
            }
        }
        return;
    }
    // ---- A_hat tile: 64 x 256, col-fast (64 col-tiles), 1KB drains ----
    int bid = blockIdx.x - 512;
    int i0 = (bid >> 6) * 64 + w * 16;               // 256 row-tiles
    int j0 = (bid & 63) * 256;                       // 64 col-tiles (fast)
    size_t arow = (size_t)(i0 + lm) * 8;
    bf16x8 a0 = Ap[arow + lg];                       // k 0..31
    bf16x8 a1 = Ap[arow + 4 + lg];                   // k 32..63
    f32x4 acc[16];
#pragma unroll
    for (int ct = 0; ct < 16; ++ct) {
        size_t brow = (size_t)(j0 + ct * 16 + lm) * 8;
        bf16x8 b0 = Ap[brow + lg];
        bf16x8 b1 = Ap[brow + 4 + lg];
        f32x4 c = {0.f, 0.f, 0.f, 0.f};
        c = __builtin_amdgcn_mfma_f32_16x16x32_bf16(a0, b0, c, 0, 0, 0);
        c = __builtin_amdgcn_mfma_f32_16x16x32_bf16(a1, b1, c, 0, 0, 0);
        acc[ct] = c;
    }
#pragma unroll
    for (int ph = 0; ph < 2; ++ph) {                 // ph: rows ph*8..ph*8+7
        if (ph == 1) {                               // WAR: ph0 reads done
            asm volatile("s_waitcnt lgkmcnt(0)" ::: "memory");
            __builtin_amdgcn_sched_barrier(0);
        }
        if ((lg >> 1) == ph) {                       // half-wave stages 8 rows
#pragma unroll
            for (int ct = 0; ct < 16; ++ct) {
                int col = ct * 16 + lm;
#pragma unroll
                for (int reg = 0; reg < 4; ++reg) {
                    float v = acc[ct][reg];
                    v = __builtin_amdgcn_rcpf(1.f + __expf(-v));
                    myl[((lg & 1) * 4 + reg) * 260 + col] = v;
                }
            }
        }
        asm volatile("s_waitcnt lgkmcnt(0)" ::: "memory");   // RAW: writes done
        __builtin_amdgcn_sched_barrier(0);
#pragma unroll
        for (int i = 0; i < 8; ++i) {                // 8 x 1KB contiguous
            f32x4 v = *reinterpret_cast<const f32x4*>(&myl[i * 260 + l * 4]);
            float* dst = &outA[(size_t)(i0 + ph * 8 + i) * NN + j0 + l * 4];
            __builtin_nontemporal_store(v, reinterpret_cast<f32x4*>(dst));
        }
    }
}

extern "C" void kernel_launch(void* const* d_in, const int* in_sizes, int n_in,
                              void* d_out, int out_size, void* d_ws, size_t ws_size,
                              hipStream_t stream) {
    const float* x     = (const float*)d_in[0];
    const int*   ei    = (const int*)d_in[1];
    // d_in[2] = adj (unused)
    const float* Wg    = (const float*)d_in[3];
    const float* att_s = (const float*)d_in[4];
    const float* att_d = (const float*)d_in[5];
    const float* bg    = (const float*)d_in[6];
    const float* W1    = (const float*)d_in[7];
    const float* b1    = (const float*)d_in[8];
    const float* W2    = (const float*)d_in[9];
    const float* b2    = (const float*)d_in[10];

    float* ws    = (float*)d_ws;
    float* a_src = ws;                              // NN
    float* a_dst = a_src + NN;                      // NN
    int*   deg   = (int*)(a_dst + NN);              // NN [memset 0]
    int*   cursor= deg + NN;                        // NN [memset 0]
    int*   row_start = cursor + NN;                 // NN+4
    int*   ssrc  = row_start + NN + 4;              // NE
    float* part  = (float*)(ssrc + NE);             // NCHK*FD*EMB = 8.4M f32
    __hip_bfloat16* xbf  = (__hip_bfloat16*)(part + (size_t)NCHK * FD * EMB); // NN*FD
    __hip_bfloat16* WgT  = xbf + (size_t)NN * FD;              // OD*FD
    __hip_bfloat16* hbf  = WgT + (size_t)OD * FD;              // NN*OD
    __hip_bfloat16* ebf  = hbf + (size_t)NN * OD;              // NN*OD
    __hip_bfloat16* h2bf = ebf + (size_t)NN * OD;              // FD*OD

    float* Ahat = (float*)d_out;
    float* Xhat = Ahat + (size_t)NN * NN;

    hipMemsetAsync(deg, 0, 2 * NN * sizeof(int), stream);
    const int prep_blocks = NCHK * 8 + NE / 256 + NN * FD / 2048 + 1;   // 7169
    k_prep<<<prep_blocks, 256, 0, stream>>>(x, xbf, Wg, WgT, ei, deg, W1, part);
    k_scan<<<1, 256, 0, stream>>>(deg, row_start);
    const int mid_blocks = NE / 256 + NN / 64 + FD / 4;            // 2432
    k_mid<<<mid_blocks, 256, 0, stream>>>(ei, row_start, cursor, ssrc,
                                          xbf, WgT, att_s, att_d,
                                          hbf, a_src, a_dst,
                                          part, b1, W2, b2, h2bf);
    k_aggcsr<<<NN / 4, 256, 0, stream>>>(row_start, ssrc, a_src, a_dst,
                                         (const u16*)hbf, bg, ebf);
    k_mmAX<<<512 + (NN / 64) * (NN / 256), 256, 0, stream>>>(ebf, h2bf, Ahat, Xhat);
}

// Round 16
// 356.910 us; speedup vs baseline: 1.2490x; 1.2490x over previous
//
#include <hip/hip_runtime.h>
#include <hip/hip_bf16.h>

#define NN 16384     // nodes
#define FD 512       // feature dim
#define EMB 128      // embed_dim (dense1)
#define OD 64        // out_dim
#define NE 524288    // edges (self-loops handled analytically)
#define NCHK 128     // xtw n-chunks (128 rows each)

typedef __bf16 bf16x8 __attribute__((ext_vector_type(8)));
typedef float f32x4 __attribute__((ext_vector_type(4)));
typedef unsigned short u16;

__device__ inline float bfu2f(u16 u) {
    unsigned int x = (unsigned int)u << 16;
    float f;
    __builtin_memcpy(&f, &x, 4);
    return f;
}

// ===== prep: xtw partials (1024 blocks, 4/CU) | dst hist | x->bf16 | WgT ===
__global__ __launch_bounds__(256) void k_prep(
    const float* __restrict__ x, __hip_bfloat16* __restrict__ xbf,
    const float* __restrict__ Wg, __hip_bfloat16* __restrict__ WgT,
    const int* __restrict__ ei, int* __restrict__ deg,
    const float* __restrict__ W1, float* __restrict__ part) {
    __shared__ float xs[4][64];
    __shared__ float wsh[4][EMB];
    int b = blockIdx.x;
    int t = threadIdx.x;
    if (b < NCHK * 8) {                              // xtw partial tile
        int fb = b & 7, nc = b >> 3;                 // 8 f-tiles x 128 n-chunks
        int f0 = fb * 64, nb = nc * 128;             // 128 rows per chunk
        int eb = (t & 15) * 8;                       // 8 e per thread
        int fbase = (t >> 4) * 4;                    // 4 f per thread
        float acc[4][8] = {};
        for (int n4 = 0; n4 < 128; n4 += 4) {        // 32 iterations
            { int nn = t >> 6, ff = t & 63;
              xs[nn][ff] = x[(size_t)(nb + n4 + nn) * FD + f0 + ff]; }
#pragma unroll
            for (int j = 0; j < 2; ++j) {
                int idx = t + j * 256;
                wsh[idx >> 7][idx & 127] = W1[(size_t)(nb + n4 + (idx >> 7)) * EMB + (idx & 127)];
            }
            __syncthreads();
#pragma unroll
            for (int nn = 0; nn < 4; ++nn) {
                float xv[4], wv[8];
#pragma unroll
                for (int i = 0; i < 4; ++i) xv[i] = xs[nn][fbase + i];
#pragma unroll
                for (int j = 0; j < 8; ++j) wv[j] = wsh[nn][eb + j];
#pragma unroll
                for (int i = 0; i < 4; ++i)
#pragma unroll
                    for (int j = 0; j < 8; ++j) acc[i][j] += xv[i] * wv[j];
            }
            __syncthreads();
        }
#pragma unroll
        for (int i = 0; i < 4; ++i) {
            float* dst = &part[((size_t)nc * FD + f0 + fbase + i) * EMB + eb];
            *reinterpret_cast<f32x4*>(dst) = *reinterpret_cast<f32x4*>(&acc[i][0]);
            *reinterpret_cast<f32x4*>(dst + 4) = *reinterpret_cast<f32x4*>(&acc[i][4]);
        }
        return;
    }
    b -= NCHK * 8;
    if (b < NE / 256) {                              // histogram of dst
        int i = b * 256 + t;
        atomicAdd(deg + ei[NE + i], 1);
        return;
    }
    b -= NE / 256;
    if (b < NN * FD / 2048) {                        // x -> bf16
        size_t i = ((size_t)b * 256 + t) * 8;
        float4 v0 = *reinterpret_cast<const float4*>(x + i);
        float4 v1 = *reinterpret_cast<const float4*>(x + i + 4);
        __hip_bfloat16 o[8];
        o[0] = __float2bfloat16(v0.x); o[1] = __float2bfloat16(v0.y);
        o[2] = __float2bfloat16(v0.z); o[3] = __float2bfloat16(v0.w);
        o[4] = __float2bfloat16(v1.x); o[5] = __float2bfloat16(v1.y);
        o[6] = __float2bfloat16(v1.z); o[7] = __float2bfloat16(v1.w);
        *reinterpret_cast<uint4*>(xbf + i) = *reinterpret_cast<const uint4*>(o);
        return;
    }
    b -= NN * FD / 2048;
    {                                                // WgT[c][k] = Wg[k][c]
        int c = t >> 2;
        int k0 = (t & 3) * 128;
        for (int j = 0; j < 128; ++j)
            WgT[c * 512 + k0 + j] = __float2bfloat16(Wg[(size_t)(k0 + j) * OD + c]);
    }
}

// ---------------- exclusive scan deg[NN] -> row_start (parallel) -----------
__global__ __launch_bounds__(256) void k_scan(const int* __restrict__ deg,
                                              int* __restrict__ row_start) {
    __shared__ int part[256];
    int t = threadIdx.x;
    int base = t * 64;                                   // NN/256 = 64
    int s = 0;
    for (int j = 0; j < 64; ++j) s += deg[base + j];
    part[t] = s;
    __syncthreads();
    for (int off = 1; off < 256; off <<= 1) {
        int v = (t >= off) ? part[t - off] : 0;
        __syncthreads();
        part[t] += v;
        __syncthreads();
    }
    int run = part[t] - s;                               // exclusive
    if (t == 255) row_start[NN] = part[255];
    for (int j = 0; j < 64; ++j) { row_start[base + j] = run; run += deg[base + j]; }
}

// ===== mid: CSR scatter | h = xbf@Wg MFMA + a_src/a_dst | h2 reduce ========
__global__ __launch_bounds__(256) void k_mid(
    const int* __restrict__ ei, const int* __restrict__ row_start,
    int* __restrict__ cursor, int* __restrict__ ssrc,
    const __hip_bfloat16* __restrict__ xbf, const __hip_bfloat16* __restrict__ WgT,
    const float* __restrict__ att_s, const float* __restrict__ att_d,
    __hip_bfloat16* __restrict__ hbf, float* __restrict__ a_src, float* __restrict__ a_dst,
    const float* __restrict__ part, const float* __restrict__ b1,
    const float* __restrict__ W2, const float* __restrict__ b2,
    __hip_bfloat16* __restrict__ h2bf) {
    __shared__ float hv[4][EMB];
    int b = blockIdx.x;
    int t = threadIdx.x;
    if (b < NE / 256) {                              // scatter
        int i = b * 256 + t;
        int d = ei[NE + i];
        int pos = atomicAdd(cursor + d, 1);
        ssrc[row_start[d] + pos] = ei[i];
        return;
    }
    b -= NE / 256;
    int w = t >> 6, l = t & 63;
    if (b < NN / 64) {                               // hmm MFMA, 64 rows/block
        int lg = l >> 4, lm = l & 15;
        int r0 = b * 64 + w * 16;
        const bf16x8* Xp = reinterpret_cast<const bf16x8*>(xbf);
        const bf16x8* Wp = reinterpret_cast<const bf16x8*>(WgT);
        bf16x8 a[16];
        size_t abase = (size_t)(r0 + lm) * 64 + lg;
#pragma unroll
        for (int kc = 0; kc < 16; ++kc) a[kc] = Xp[abase + kc * 4];
        f32x4 acc[4];
#pragma unroll
        for (int j = 0; j < 4; ++j) {
            f32x4 c = {0.f, 0.f, 0.f, 0.f};
            size_t bbase = (size_t)(j * 16 + lm) * 64 + lg;
#pragma unroll
            for (int kc = 0; kc < 16; ++kc)
                c = __builtin_amdgcn_mfma_f32_16x16x32_bf16(a[kc], Wp[bbase + kc * 4], c, 0, 0, 0);
            acc[j] = c;
        }
#pragma unroll
        for (int j = 0; j < 4; ++j)
#pragma unroll
            for (int reg = 0; reg < 4; ++reg)
                hbf[(size_t)(r0 + lg * 4 + reg) * OD + j * 16 + lm] = __float2bfloat16(acc[j][reg]);
        float ats0 = att_s[lm], ats1 = att_s[16 + lm], ats2 = att_s[32 + lm], ats3 = att_s[48 + lm];
        float atd0 = att_d[lm], atd1 = att_d[16 + lm], atd2 = att_d[32 + lm], atd3 = att_d[48 + lm];
#pragma unroll
        for (int reg = 0; reg < 4; ++reg) {
            float ps = acc[0][reg] * ats0 + acc[1][reg] * ats1 + acc[2][reg] * ats2 + acc[3][reg] * ats3;
            float pd = acc[0][reg] * atd0 + acc[1][reg] * atd1 + acc[2][reg] * atd2 + acc[3][reg] * atd3;
#pragma unroll
            for (int off = 1; off < 16; off <<= 1) {
                ps += __shfl_xor(ps, off, 64);
                pd += __shfl_xor(pd, off, 64);
            }
            if (lm == 0) {
                int r = r0 + lg * 4 + reg;
                a_src[r] = ps;
                a_dst[r] = pd;
            }
        }
        return;
    }
    b -= NN / 64;
    {                                                // h2: reduce 128 partials
        int f = b * 4 + w;
        float s0 = 0.f, s1 = 0.f;
        for (int nc = 0; nc < NCHK; ++nc) {
            const float* p = part + ((size_t)nc * FD + f) * EMB;
            s0 += p[l];
            s1 += p[l + 64];
        }
        s0 += b1[l]; s1 += b1[l + 64];
        hv[w][l] = s0 > 0.f ? s0 : 0.f;
        hv[w][l + 64] = s1 > 0.f ? s1 : 0.f;
        __syncthreads();
        float acc = b2[l];
        const float* myhv = hv[w];
        for (int e = 0; e < EMB; ++e)
            acc += myhv[e] * W2[e * OD + l];
        h2bf[(size_t)f * OD + l] = __float2bfloat16(acc);
    }
}

// ------- fused softmax+aggregate+bias+leaky+bf16: one wave per dst node ----
__global__ __launch_bounds__(256) void k_aggcsr(
    const int* __restrict__ row_start, const int* __restrict__ ssrc,
    const float* __restrict__ a_src, const float* __restrict__ a_dst,
    const u16* __restrict__ hb, const float* __restrict__ bg,
    __hip_bfloat16* __restrict__ ebf) {
    int node = blockIdx.x * 4 + (threadIdx.x >> 6);
    int lane = threadIdx.x & 63;
    float ad = a_dst[node];
    float e0 = a_src[node] + ad;                 // self loop
    e0 = e0 > 0.f ? e0 : 0.5f * e0;
    float p0 = __expf(e0);
    float denom = p0;
    float acc = p0 * bfu2f(hb[(size_t)node * OD + lane]);
    int j0 = row_start[node], j1 = row_start[node + 1];
    int j = j0;
    for (; j + 2 <= j1; j += 2) {
        int sA = ssrc[j], sB = ssrc[j + 1];
        float hA = bfu2f(hb[(size_t)sA * OD + lane]);
        float hB = bfu2f(hb[(size_t)sB * OD + lane]);
        float eA = a_src[sA] + ad, eB = a_src[sB] + ad;
        eA = eA > 0.f ? eA : 0.5f * eA;
        eB = eB > 0.f ? eB : 0.5f * eB;
        float pA = __expf(eA), pB = __expf(eB);
        denom += pA + pB;
        acc += pA * hA + pB * hB;
    }
    if (j < j1) {
        int s = ssrc[j];
        float e = a_src[s] + ad;
        e = e > 0.f ? e : 0.5f * e;
        float pv = __expf(e);
        denom += pv;
        acc += pv * bfu2f(hb[(size_t)s * OD + lane]);
    }
    float v = acc * __builtin_amdgcn_rcpf(denom) + bg[lane];
    v = v > 0.f ? v : 0.01f * v;                 // embed leaky_relu 0.01
    ebf[(size_t)node * OD + lane] = __float2bfloat16(v);
}

// ===== merged output GEMMs: X_hat tiles (512 blocks) then A_hat (16384) ====
__global__ __launch_bounds__(256) void k_mmAX(const __hip_bfloat16* __restrict__ ebf,
                                              const __hip_bfloat16* __restrict__ h2bf,
                                              float* __restrict__ outA,
                                              float* __restrict__ outX) {
    __shared__ float ls[4][2176];                    // max(32*68, 16*132) floats
    int w = threadIdx.x >> 6, l = threadIdx.x & 63;
    int lg = l >> 4, lm = l & 15;
    float* myl = ls[w];
    const bf16x8* Ap = reinterpret_cast<const bf16x8*>(ebf);
    if (blockIdx.x < 512) {                          // ---- X_hat tile ----
        int bid = blockIdx.x;
        int i0 = (bid >> 2) * 128 + w * 32;
        int j0 = (bid & 3) * 128;
        const bf16x8* Bp = reinterpret_cast<const bf16x8*>(h2bf);
        size_t arow = (size_t)(i0 + lm) * 8;
        bf16x8 a0 = Ap[arow + lg];
        bf16x8 a1 = Ap[arow + 4 + lg];
        bf16x8 a2 = Ap[arow + 128 + lg];
        bf16x8 a3 = Ap[arow + 128 + 4 + lg];
        f32x4 accL[8], accH[8];
#pragma unroll
        for (int ct = 0; ct < 8; ++ct) {
            size_t brow = (size_t)(j0 + ct * 16 + lm) * 8;
            bf16x8 b0 = Bp[brow + lg];
            bf16x8 b1 = Bp[brow + 4 + lg];
            f32x4 cL = {0.f, 0.f, 0.f, 0.f};
            f32x4 cH = {0.f, 0.f, 0.f, 0.f};
            cL = __builtin_amdgcn_mfma_f32_16x16x32_bf16(a0, b0, cL, 0, 0, 0);
            cL = __builtin_amdgcn_mfma_f32_16x16x32_bf16(a1, b1, cL, 0, 0, 0);
            cH = __builtin_amdgcn_mfma_f32_16x16x32_bf16(a2, b0, cH, 0, 0, 0);
            cH = __builtin_amdgcn_mfma_f32_16x16x32_bf16(a3, b1, cH, 0, 0, 0);
            accL[ct] = cL;
            accH[ct] = cH;
        }
#pragma unroll
        for (int ph = 0; ph < 2; ++ph) {
            if (ph == 1) {
                asm volatile("s_waitcnt lgkmcnt(0)" ::: "memory");
                __builtin_amdgcn_sched_barrier(0);
            }
#pragma unroll
            for (int c4 = 0; c4 < 4; ++c4) {
                int ct = ph * 4 + c4;
                int col = c4 * 16 + lm;
#pragma unroll
                for (int reg = 0; reg < 4; ++reg) {
                    int row = lg * 4 + reg;
                    myl[row * 68 + col] = accL[ct][reg];
                    myl[(row + 16) * 68 + col] = accH[ct][reg];
                }
            }
            asm volatile("s_waitcnt lgkmcnt(0)" ::: "memory");
            __builtin_amdgcn_sched_barrier(0);
#pragma unroll
            for (int i = 0; i < 8; ++i) {
                int row = i * 4 + lg;
                f32x4 v = *reinterpret_cast<const f32x4*>(&myl[row * 68 + lm * 4]);
                float* dst = &outX[(size_t)(i0 + row) * FD + j0 + ph * 64 + lm * 4];
                __builtin_nontemporal_store(v, reinterpret_cast<f32x4*>(dst));
            }
        }
        return;
    }
    // ---- A_hat tile (R8 col-fast mapping, R13 row-split drain) ----
    int bid = blockIdx.x - 512;
    int i0 = (bid >> 7) * 128 + w * 32;
    int j0 = (bid & 127) * 128;
    size_t arow = (size_t)(i0 + lm) * 8;
    bf16x8 a0 = Ap[arow + lg];
    bf16x8 a1 = Ap[arow + 4 + lg];
    bf16x8 a2 = Ap[arow + 128 + lg];
    bf16x8 a3 = Ap[arow + 128 + 4 + lg];
    f32x4 accL[8], accH[8];
#pragma unroll
    for (int ct = 0; ct < 8; ++ct) {
        size_t brow = (size_t)(j0 + ct * 16 + lm) * 8;
        bf16x8 b0 = Ap[brow + lg];
        bf16x8 b1 = Ap[brow + 4 + lg];
        f32x4 cL = {0.f, 0.f, 0.f, 0.f};
        f32x4 cH = {0.f, 0.f, 0.f, 0.f};
        cL = __builtin_amdgcn_mfma_f32_16x16x32_bf16(a0, b0, cL, 0, 0, 0);
        cL = __builtin_amdgcn_mfma_f32_16x16x32_bf16(a1, b1, cL, 0, 0, 0);
        cH = __builtin_amdgcn_mfma_f32_16x16x32_bf16(a2, b0, cH, 0, 0, 0);
        cH = __builtin_amdgcn_mfma_f32_16x16x32_bf16(a3, b1, cH, 0, 0, 0);
        accL[ct] = cL;
        accH[ct] = cH;
    }
#pragma unroll
    for (int ph = 0; ph < 2; ++ph) {                 // ph0: rows 0-15 (accL)
        if (ph == 1) {                               // WAR: ph0 reads done
            asm volatile("s_waitcnt lgkmcnt(0)" ::: "memory");
            __builtin_amdgcn_sched_barrier(0);
        }
#pragma unroll
        for (int ct = 0; ct < 8; ++ct) {             // stage 16 rows x 128 cols
            int col = ct * 16 + lm;
#pragma unroll
            for (int reg = 0; reg < 4; ++reg) {
                float v = ph ? accH[ct][reg] : accL[ct][reg];
                v = __builtin_amdgcn_rcpf(1.f + __expf(-v));
                myl[(lg * 4 + reg) * 132 + col] = v;
            }
        }
        asm volatile("s_waitcnt lgkmcnt(0)" ::: "memory");   // RAW: writes done
        __builtin_amdgcn_sched_barrier(0);
#pragma unroll
        for (int i = 0; i < 8; ++i) {                // 2 rows x 512B per instr
            int row = i * 2 + (l >> 5);
            int c4 = (l & 31) * 4;
            f32x4 v = *reinterpret_cast<const f32x4*>(&myl[row * 132 + c4]);
            float* dst = &outA[(size_t)(i0 + ph * 16 + row) * NN + j0 + c4];
            __builtin_nontemporal_store(v, reinterpret_cast<f32x4*>(dst));
        }
    }
}

extern "C" void kernel_launch(void* const* d_in, const int* in_sizes, int n_in,
                              void* d_out, int out_size, void* d_ws, size_t ws_size,
                              hipStream_t stream) {
    const float* x     = (const float*)d_in[0];
    const int*   ei    = (const int*)d_in[1];
    // d_in[2] = adj (unused)
    const float* Wg    = (const float*)d_in[3];
    const float* att_s = (const float*)d_in[4];
    const float* att_d = (const float*)d_in[5];
    const float* bg    = (const float*)d_in[6];
    const float* W1    = (const float*)d_in[7];
    const float* b1    = (const float*)d_in[8];
    const float* W2    = (const float*)d_in[9];
    const float* b2    = (const float*)d_in[10];

    float* ws    = (float*)d_ws;
    float* a_src = ws;                              // NN
    float* a_dst = a_src + NN;                      // NN
    int*   deg   = (int*)(a_dst + NN);              // NN [memset 0]
    int*   cursor= deg + NN;                        // NN [memset 0]
    int*   row_start = cursor + NN;                 // NN+4
    int*   ssrc  = row_start + NN + 4;              // NE
    float* part  = (float*)(ssrc + NE);             // NCHK*FD*EMB = 8.4M f32
    __hip_bfloat16* xbf  = (__hip_bfloat16*)(part + (size_t)NCHK * FD * EMB); // NN*FD
    __hip_bfloat16* WgT  = xbf + (size_t)NN * FD;              // OD*FD
    __hip_bfloat16* hbf  = WgT + (size_t)OD * FD;              // NN*OD
    __hip_bfloat16* ebf  = hbf + (size_t)NN * OD;              // NN*OD
    __hip_bfloat16* h2bf = ebf + (size_t)NN * OD;              // FD*OD

    float* Ahat = (float*)d_out;
    float* Xhat = Ahat + (size_t)NN * NN;

    hipMemsetAsync(deg, 0, 2 * NN * sizeof(int), stream);
    const int prep_blocks = NCHK * 8 + NE / 256 + NN * FD / 2048 + 1;   // 7169
    k_prep<<<prep_blocks, 256, 0, stream>>>(x, xbf, Wg, WgT, ei, deg, W1, part);
    k_scan<<<1, 256, 0, stream>>>(deg, row_start);
    const int mid_blocks = NE / 256 + NN / 64 + FD / 4;            // 2432
    k_mid<<<mid_blocks, 256, 0, stream>>>(ei, row_start, cursor, ssrc,
                                          xbf, WgT, att_s, att_d,
                                          hbf, a_src, a_dst,
                                          part, b1, W2, b2, h2bf);
    k_aggcsr<<<NN / 4, 256, 0, stream>>>(row_start, ssrc, a_src, a_dst,
                                         (const u16*)hbf, bg, ebf);
    k_mmAX<<<512 + (NN / 128) * (NN / 128), 256, 0, stream>>>(ebf, h2bf, Ahat, Xhat);
}